// Round 14
// baseline (48.469 us; speedup 1.0000x reference)
//
#include <hip/hip_runtime.h>

// Bilinear flow warp, LDS row-tile v9 = R6 base (best, 44.4us) + micro-opts.
// images [32,3,512,512] f32, flows [32,2,512,512] f32 (ch0=dy, ch1=dx).
//
// R13 post-mortem: float2-I/O 16px/thread regressed (VGPR 116 -> occ 20%,
// conflicts 5.5M). Plateau 44-47us across 5 structural variants; R6 is best.
// This round: exact R6 structure (TH=8, 512thr, single buffer,
// global_load_lds staging, plain __syncthreads) plus:
//  1. lerp-form blend: h0=fma(dx,Ic-Ia,Ia); h1=fma(dx,Id-Ib,Ib);
//     r=fma(dy,h1-h0,h0) -- 6 VALU/px, no per-channel weight recompute.
//  2. nontemporal flow loads: flows are 67MB read-once; keeping them out of
//     L3 shrinks the working set (267MB -> ~200MB vs 256MB L3) to cut the
//     82MB/replay steady-state HBM re-fetch.
// If this is within noise of 44.4, the structure is at its practical
// plateau (balanced LDS/VMEM/L3 mix, no pipe >60%).

constexpr int C = 3, H = 512, W = 512, HW = H * W;
constexpr int TH = 8, HALO = 4;
constexpr int LROWS = TH + 2 * HALO;      // 16 staged rows
constexpr int LWP   = W;                  // 512: stride == 0 mod 32 banks
constexpr int TILES = 32 * (H / TH);      // 2048 blocks, %8 == 0

__global__ __launch_bounds__(512) void warp_bilinear_rows(
    const float* __restrict__ images,
    const float* __restrict__ flows,
    float* __restrict__ out)
{
    __shared__ float tile[LROWS * LWP];   // 32,768 B

    // XCD-contiguous: XCD r owns tiles [r*256,(r+1)*256) = 4 whole batches.
    int bid = blockIdx.x;
    int tile_id = (bid & 7) * (TILES / 8) + (bid >> 3);
    int b   = tile_id >> 6;               // 64 row-tiles per batch
    int ty0 = (tile_id & 63) * TH;

    int tid = threadIdx.x;                // 0..511 = my column

    // ---- flow load (nontemporal) + gather state (8 px/thread) ----
    const float* flow_y = flows + (size_t)b * 2 * HW + ty0 * W + tid;
    const float* flow_x = flow_y + HW;

    float dxv[TH], dyv[TH];
    int   li[TH];
    unsigned okm = 0;
#pragma unroll
    for (int k = 0; k < TH; ++k) {
        float fy = __builtin_nontemporal_load(flow_y + k * W);
        float fx = __builtin_nontemporal_load(flow_x + k * W);
        float sx = fminf(fmaxf((float)tid + fx, 0.0f), (float)(W - 1));
        float sy = fminf(fmaxf((float)(ty0 + k) + fy, 0.0f), (float)(H - 1));
        int x0 = min((int)sx, W - 2);     // sx >= 0 so (int) == floor
        int y0 = min((int)sy, H - 2);
        dxv[k] = sx - (float)x0;
        dyv[k] = sy - (float)y0;
        int ly0 = y0 - (ty0 - HALO);
        bool ok = (ly0 >= 0) & (ly0 <= LROWS - 2);
        okm |= (unsigned)ok << k;
        li[k] = ok ? (ly0 * LWP + x0)     // LDS offset (x needs no halo)
                   : (y0 * W + x0);       // global fallback offset
    }
    bool fast = __all(okm == ((1u << TH) - 1));

    // staging addresses (channel-invariant): wave-uniform row + lane*16B
    int srow[LROWS / 4];
    int scol = (tid & 127) * 4;
#pragma unroll
    for (int it = 0; it < LROWS / 4; ++it) {
        int r = it * 4 + (tid >> 7);
        srow[it] = min(max(ty0 - HALO + r, 0), H - 1);
    }

    for (int c = 0; c < C; ++c) {
        const float* gimg = images + ((size_t)b * C + c) * HW;
        __syncthreads();                  // previous channel's reads done
#pragma unroll
        for (int it = 0; it < LROWS / 4; ++it) {
            int r = it * 4 + (tid >> 7);
            __builtin_amdgcn_global_load_lds(
                (const __attribute__((address_space(1))) void*)(gimg + srow[it] * W + scol),
                (__attribute__((address_space(3))) void*)(&tile[r * LWP + scol]),
                16, 0, 0);
        }
        __syncthreads();                  // drains vmcnt -> tile ready

        float* outc = out + ((size_t)b * C + c) * HW + ty0 * W + tid;
        if (fast) {
#pragma unroll
            for (int k = 0; k < TH; ++k) {
                int t = li[k];
                float Ia = tile[t];        float Ic = tile[t + 1];
                float Ib = tile[t + LWP];  float Id = tile[t + LWP + 1];
                float h0 = fmaf(dxv[k], Ic - Ia, Ia);   // lerp along x, row y0
                float h1 = fmaf(dxv[k], Id - Ib, Ib);   // lerp along x, row y1
                __builtin_nontemporal_store(
                    fmaf(dyv[k], h1 - h0, h0), outc + k * W);
            }
        } else {                           // rare: |dy| > ~4 near strip edge
#pragma unroll
            for (int k = 0; k < TH; ++k) {
                float Ia, Ib, Ic, Id;
                if ((okm >> k) & 1) {
                    int t = li[k];
                    Ia = tile[t];        Ic = tile[t + 1];
                    Ib = tile[t + LWP];  Id = tile[t + LWP + 1];
                } else {
                    int g = li[k];
                    Ia = gimg[g];        Ic = gimg[g + 1];
                    Ib = gimg[g + W];    Id = gimg[g + W + 1];
                }
                float h0 = fmaf(dxv[k], Ic - Ia, Ia);
                float h1 = fmaf(dxv[k], Id - Ib, Ib);
                __builtin_nontemporal_store(
                    fmaf(dyv[k], h1 - h0, h0), outc + k * W);
            }
        }
    }
}

extern "C" void kernel_launch(void* const* d_in, const int* in_sizes, int n_in,
                              void* d_out, int out_size, void* d_ws, size_t ws_size,
                              hipStream_t stream) {
    const float* images = (const float*)d_in[0];
    const float* flows  = (const float*)d_in[1];
    float* out = (float*)d_out;

    dim3 block(512);
    dim3 grid(TILES);                     // 2048 blocks
    hipLaunchKernelGGL(warp_bilinear_rows, grid, block, 0, stream,
                       images, flows, out);
}